// Round 5
// baseline (521.715 us; speedup 1.0000x reference)
//
#include <hip/hip_runtime.h>
#include <math.h>

#define B_   4
#define N_   6
#define CIN  512
#define CT   64
#define Dd   41
#define FH   16
#define FW   44
#define NPIX (FH*FW)      // 704
#define NO   (Dd+CT)      // 105
#define NOP  112          // padded outputs for WdT
#define NXX  128
#define NYY  128
#define NZZ  1
#define TOT  (B_*NZZ*NYY*NXX)   // 65536
#define NPTS (B_*N_*Dd*NPIX)    // 692736
#define NCHUNK ((NPTS+63)/64)   // 10824

#define PIXT 64
#define NTILE (NPIX/PIXT) // 11

#define PK_INVALID 0xFFFFFFFFu

// ---------------- helpers ----------------

__device__ __forceinline__ void inv3(const double* m, double* o) {
    double a=m[0],b=m[1],c=m[2],d=m[3],e=m[4],f=m[5],g=m[6],h=m[7],i=m[8];
    double A  =  (e*i - f*h);
    double Bc = -(d*i - f*g);
    double Cc =  (d*h - e*g);
    double det = a*A + b*Bc + c*Cc;
    double inv = 1.0/det;
    o[0]=A*inv;            o[1]=-(b*i - c*h)*inv;  o[2]= (b*f - c*e)*inv;
    o[3]=Bc*inv;           o[4]= (a*i - c*g)*inv;  o[5]=-(a*f - c*d)*inv;
    o[6]=Cc*inv;           o[7]=-(a*h - b*g)*inv;  o[8]= (a*e - b*d)*inv;
}

// geometry for one point (d, pixel) of camera bn; returns vox or -1.
__device__ __forceinline__ int point_vox(const double* tfp, int b, int d, int hh, int ww) {
    const double DXD = (double)0.8f;
    const double LOX = (double)(-50.8f) - DXD*0.5;
    const double LOY = LOX;
    const double DZD = 20.0;
    const double LOZ = -10.0;
    double fx = (double)((float)(ww * (703.0/43.0)));
    double fy = (double)((float)(hh * 17.0));
    double fz = 4.0 + (double)d;
    double px = fx - tfp[21], py = fy - tfp[22], pz = fz - tfp[23];
    double qx = tfp[ 9]*px + tfp[10]*py + tfp[11]*pz;
    double qy = tfp[12]*px + tfp[13]*py + tfp[14]*pz;
    double qz = tfp[15]*px + tfp[16]*py + tfp[17]*pz;
    double rx = qx*qz, ry = qy*qz, rz = qz;
    double sx = tfp[0]*rx + tfp[1]*ry + tfp[2]*rz + tfp[18];
    double sy = tfp[3]*rx + tfp[4]*ry + tfp[5]*rz + tfp[19];
    double sz = tfp[6]*rx + tfp[7]*ry + tfp[8]*rz + tfp[20];
    int gx = (int)((sx - LOX) / DXD);
    int gy = (int)((sy - LOY) / DXD);
    int gz = (int)((sz - LOZ) / DZD);
    bool kept = (gx>=0) & (gx<NXX) & (gy>=0) & (gy<NYY) & (gz>=0) & (gz<NZZ);
    return kept ? (((b*NZZ + gz)*NYY + gy)*NXX + gx) : -1;
}

// ---------------- kernel A: per-(b,n) transforms (double) ----------------
__global__ void tf_kernel(const float* __restrict__ rots,
                          const float* __restrict__ trans,
                          const float* __restrict__ intrins,
                          const float* __restrict__ post_rots,
                          const float* __restrict__ post_trans,
                          double* __restrict__ tf) {
    int bn = threadIdx.x;
    if (bn >= B_*N_) return;
    double k[9], pr[9], r[9], ik[9], ipr[9], c[9];
    for (int i=0;i<9;i++) { k[i]=intrins[bn*9+i]; pr[i]=post_rots[bn*9+i]; r[i]=rots[bn*9+i]; }
    inv3(k, ik);
    inv3(pr, ipr);
    for (int i=0;i<3;i++)
        for (int j=0;j<3;j++) {
            double s = 0.0;
            for (int kk=0;kk<3;kk++) s += r[i*3+kk]*ik[kk*3+j];
            c[i*3+j] = s;
        }
    double* o = tf + bn*24;
    for (int i=0;i<9;i++) o[i]   = c[i];
    for (int i=0;i<9;i++) o[9+i] = ipr[i];
    for (int i=0;i<3;i++) o[18+i] = (double)trans[bn*3+i];
    for (int i=0;i<3;i++) o[21+i] = (double)post_trans[bn*3+i];
}

// ---------------- kernel A2: transpose Wd[105][512] -> WdT[512][112] (pad 0) ------
__global__ __launch_bounds__(256) void wdt_kernel(const float* __restrict__ Wd,
                                                  float* __restrict__ WdT) {
    int idx = blockIdx.x * 256 + threadIdx.x;
    if (idx >= CIN*NOP) return;
    int k = idx / NOP;
    int o = idx % NOP;
    WdT[idx] = (o < NO) ? Wd[o*CIN + k] : 0.0f;
}

// ---------------- kernel B: GEMM (scalar weights) + softmax + geometry ------------
// grid = B*N * NTILE * 2.  Block: 256 thr = 4 waves, 64 pixels.
// half 0: outputs 0..52  (o0 = wv*16, keep o<53)  + softmax + w_arr + pk + hist
// half 1: outputs 53..104 (o0 = 48+wv*16, keep 53<=o<105) -> featc ch 12..63
__global__ __launch_bounds__(256) void feat_kernel(
    const float* __restrict__ x, const float* __restrict__ WdT,
    const float* __restrict__ bd, const double* __restrict__ tf,
    float* __restrict__ featc, unsigned* __restrict__ pk_arr,
    float* __restrict__ w_arr, int* __restrict__ hist)
{
    __shared__ float  s_dep[Dd*65];      // depth rows (half0)          10.7 KB
    __shared__ float  s_cvt[CT*65];      // cvt rows (c = o-41)         16.6 KB
    __shared__ float  s_red[4*PIXT];
    __shared__ float  s_inv[PIXT];
    __shared__ double s_tf[24];

    const int t    = threadIdx.x;
    const int l    = t & 63;             // lane = pixel within tile
    const int wv   = t >> 6;             // wave 0..3
    const int bid  = blockIdx.x;
    const int bn   = bid / (NTILE*2);
    const int r    = bid % (NTILE*2);
    const int tile = r >> 1;
    const int half = r & 1;
    const int pix0 = tile * PIXT;
    const int b    = bn / N_;

    if (t < 24) s_tf[t] = tf[bn*24 + t];

    const int o0  = half*48 + wv*16;                       // 64B-aligned rows
    const int o0u = __builtin_amdgcn_readfirstlane(o0);
    const float* wbase = WdT + o0u;

    float acc[16];
    #pragma unroll
    for (int j=0;j<16;j++) acc[j] = 0.0f;

    const float* xcol = x + (size_t)bn * CIN * NPIX + pix0 + l;

    float xa[16], xb[16];
    #pragma unroll
    for (int j=0;j<16;j++) xa[j] = xcol[(size_t)j*NPIX];

    for (int k0 = 0; k0 < CIN; k0 += 32) {
        #pragma unroll
        for (int j=0;j<16;j++) xb[j] = xcol[(size_t)(k0+16+j)*NPIX];
        #pragma unroll
        for (int kk=0; kk<16; kk++) {
            const float* wr = wbase + (k0+kk)*NOP;
            #pragma unroll
            for (int j=0;j<16;j++) acc[j] = fmaf(wr[j], xa[kk], acc[j]);
        }
        if (k0 + 32 < CIN) {
            #pragma unroll
            for (int j=0;j<16;j++) xa[j] = xcol[(size_t)(k0+32+j)*NPIX];
        }
        #pragma unroll
        for (int kk=0; kk<16; kk++) {
            const float* wr = wbase + (k0+16+kk)*NOP;
            #pragma unroll
            for (int j=0;j<16;j++) acc[j] = fmaf(wr[j], xb[kk], acc[j]);
        }
    }

    // epilogue: bias + route to LDS
    const int olo = half ? 53 : 0;
    const int ohi = half ? NO : 53;
    #pragma unroll
    for (int j=0;j<16;j++) {
        int o = o0 + j;
        if (o >= olo && o < ohi) {
            float v = acc[j] + bd[o];
            if (o < Dd) s_dep[o*65 + l] = v;        // half0 only
            else        s_cvt[(o-Dd)*65 + l] = v;
        }
    }
    __syncthreads();

    if (half == 0) {
        // ---- softmax over 41 depth rows, per pixel l ----
        const int q = wv;    // 0..3
        float m = -3.0e38f;
        for (int d=q; d<Dd; d+=4) m = fmaxf(m, s_dep[d*65+l]);
        s_red[q*PIXT+l] = m;
        __syncthreads();
        if (q == 0) {
            float mm = s_red[l];
            #pragma unroll
            for (int i=1;i<4;i++) mm = fmaxf(mm, s_red[i*PIXT+l]);
            s_red[l] = mm;            // reuse row 0 as max
        }
        __syncthreads();
        {
            float mm = s_red[l];
            float ssum = 0.0f;
            for (int d=q; d<Dd; d+=4) {
                float e = expf(s_dep[d*65+l] - mm);
                s_dep[d*65+l] = e;
                ssum += e;
            }
            s_red[q*PIXT+l] = (q==0) ? ssum : ssum;   // note: row0 overwritten after read
        }
        __syncthreads();
        if (q == 0) {
            float s = 0.0f;
            #pragma unroll
            for (int i=0;i<4;i++) s += s_red[i*PIXT+l];
            s_inv[l] = 1.0f / s;
        }
        __syncthreads();

        // ---- w_arr + pk + hist for 41*64 points ----
        for (int id = t; id < Dd*PIXT; id += 256) {
            int d  = id >> 6;
            int pp = id & 63;
            int pixg = pix0 + pp;
            int hh = pixg / FW, ww = pixg % FW;
            int pt = (bn*Dd + d)*NPIX + pixg;
            w_arr[pt] = s_dep[d*65+pp] * s_inv[pp];
            int vox = point_vox(s_tf, b, d, hh, ww);
            unsigned pix_id = (unsigned)(bn*NPIX + pixg);      // < 2^15
            pk_arr[pt] = (vox >= 0) ? (((unsigned)vox << 15) | pix_id) : PK_INVALID;
            if (vox >= 0) atomicAdd(&hist[vox], 1);
        }

        // ---- featc channels 0..11 (o = 41..52), coalesced-ish ----
        for (int idx = t; idx < PIXT*12; idx += 256) {
            int p  = idx / 12;
            int cc = idx % 12;
            featc[((size_t)(bn*NPIX + pix0 + p))*CT + cc] = s_cvt[cc*65 + p];
        }
    } else {
        // ---- featc channels 12..63 (o = 53..104) ----
        for (int idx = t; idx < PIXT*52; idx += 256) {
            int p  = idx / 52;
            int cc = idx % 52;
            int c  = 12 + cc;
            featc[((size_t)(bn*NPIX + pix0 + p))*CT + c] = s_cvt[c*65 + p];
        }
    }
}

// ---------------- kernel C: exclusive scan over 65536 bins -> cursor ----------------
__global__ __launch_bounds__(1024) void scan_kernel(const int* __restrict__ hist,
                                                    int* __restrict__ cursor) {
    __shared__ int s[1024];
    const int t = threadIdx.x;
    const int CHUNK = TOT / 1024;   // 64
    int base_idx = t * CHUNK;
    int sum = 0;
    int local[64];
    #pragma unroll 8
    for (int j=0;j<CHUNK;j++) { local[j] = hist[base_idx+j]; sum += local[j]; }
    s[t] = sum;
    __syncthreads();
    for (int off=1; off<1024; off<<=1) {
        int v = (t >= off) ? s[t-off] : 0;
        __syncthreads();
        s[t] += v;
        __syncthreads();
    }
    int run = (t==0) ? 0 : s[t-1];
    #pragma unroll 8
    for (int j=0;j<CHUNK;j++) {
        cursor[base_idx+j] = run;
        run += local[j];
    }
}

// ---------------- kernel D: scatter packed records into sorted order ----------------
__global__ __launch_bounds__(256) void scatter_idx_kernel(
    const unsigned* __restrict__ pk_arr, const float* __restrict__ w_arr,
    int* __restrict__ cursor, unsigned* __restrict__ spk,
    float* __restrict__ sw)
{
    int pt = blockIdx.x * 256 + threadIdx.x;
    if (pt >= NPTS) return;
    unsigned pk = pk_arr[pt];
    if (pk != PK_INVALID) {
        int v = pk >> 15;
        int pos = atomicAdd(&cursor[v], 1);
        spk[pos] = pk;
        sw[pos]  = w_arr[pt];
    }
}

// ---------------- kernel E: balanced segmented gather -> scat[vox][ct] ----------------
__global__ __launch_bounds__(256) void gather_kernel(
    const unsigned* __restrict__ spk, const float* __restrict__ sw,
    const int* __restrict__ cursor, const float* __restrict__ featc,
    float* __restrict__ scat)
{
    const int t  = threadIdx.x;
    const int wv = t >> 6;
    const int l  = t & 63;
    const int chunk = blockIdx.x * 4 + wv;
    const int base  = chunk * 64;
    const int Np = cursor[TOT-1];          // total valid points
    if (base >= Np) return;
    int cnt = Np - base; if (cnt > 64) cnt = 64;

    unsigned pk = 0; float w = 0.0f;
    if (l < cnt) { pk = spk[base + l]; w = sw[base + l]; }
    unsigned pkm = __shfl(pk, (l == 0) ? 0 : (l - 1));
    unsigned long long starts =
        __ballot((l > 0) && (l < cnt) && ((pk >> 15) != (pkm >> 15)));

    unsigned long long m = starts;
    int rs = 0;
    while (rs < cnt) {
        int re = m ? (__ffsll((unsigned long long)m) - 1) : cnt;
        if (m) m &= m - 1;
        float acc = 0.0f;
        for (int j = rs; j < re; j++) {
            unsigned pkj = __shfl(pk, j);
            float    wj  = __shfl(w, j);
            unsigned id  = pkj & 0x7FFFu;
            acc += wj * featc[(size_t)id * CT + l];
        }
        unsigned vrun = __shfl(pk, rs) >> 15;
        float* dst = scat + (size_t)vrun * CT + l;
        if (rs == 0 || re == cnt) {
            unsafeAtomicAdd(dst, acc);      // run may continue in adjacent chunk
        } else {
            *dst = acc;                     // voxel wholly owned by this chunk
        }
        rs = re;
    }
}

// ---------------- kernel F: transpose (b,pix,ct) -> (b,ct,pix) ----------------
__global__ __launch_bounds__(256) void transpose_k(const float* __restrict__ scat,
                                                   float* __restrict__ out) {
    __shared__ float tile[64][65];
    int b  = blockIdx.x >> 8;
    int t0 = (blockIdx.x & 255) * 64;
    const float* src = scat + (size_t)b * (NYY*NXX) * CT;
    #pragma unroll
    for (int i=0;i<16;i++) {
        int idx = threadIdx.x + i*256;
        int p = idx >> 6, c = idx & 63;
        tile[p][c] = src[(size_t)(t0+p)*CT + c];
    }
    __syncthreads();
    float* dst = out + (size_t)b * CT * (NYY*NXX);
    #pragma unroll
    for (int i=0;i<16;i++) {
        int idx = threadIdx.x + i*256;
        int c = idx >> 6, p = idx & 63;
        dst[(size_t)c*(NYY*NXX) + t0 + p] = tile[p][c];
    }
}

// ---------------- launcher ----------------
extern "C" void kernel_launch(void* const* d_in, const int* in_sizes, int n_in,
                              void* d_out, int out_size, void* d_ws, size_t ws_size,
                              hipStream_t stream) {
    const float* x          = (const float*)d_in[0];
    const float* rots       = (const float*)d_in[1];
    const float* trans      = (const float*)d_in[2];
    const float* intrins    = (const float*)d_in[3];
    const float* post_rots  = (const float*)d_in[4];
    const float* post_trans = (const float*)d_in[5];
    const float* Wd         = (const float*)d_in[6];
    const float* bd         = (const float*)d_in[7];
    float* out = (float*)d_out;

    char* ws = (char*)d_ws;
    float*    featc  = (float*)ws;     ws += (size_t)B_*N_*NPIX*CT*4;   // 4.33 MB
    unsigned* pk_arr = (unsigned*)ws;  ws += (size_t)NPTS*4;            // 2.77 MB
    float*    w_arr  = (float*)ws;     ws += (size_t)NPTS*4;            // 2.77 MB
    unsigned* spk    = (unsigned*)ws;  ws += (size_t)NPTS*4;            // 2.77 MB
    float*    sw     = (float*)ws;     ws += (size_t)NPTS*4;            // 2.77 MB
    float*    scat   = (float*)ws;     ws += (size_t)TOT*CT*4;          // 16.78 MB
    int*      hist   = (int*)ws;       ws += (size_t)TOT*4;             // 0.26 MB
    int*      cursor = (int*)ws;       ws += (size_t)TOT*4;             // 0.26 MB
    double*   tf     = (double*)ws;    ws += (size_t)B_*N_*24*8;        // 4.6 KB
    float*    WdT    = (float*)ws;     ws += (size_t)CIN*NOP*4;         // 0.23 MB

    hipMemsetAsync(scat, 0, (size_t)TOT*CT*4, stream);
    hipMemsetAsync(hist, 0, (size_t)TOT*4, stream);
    tf_kernel<<<1, 64, 0, stream>>>(rots, trans, intrins, post_rots, post_trans, tf);
    wdt_kernel<<<(CIN*NOP+255)/256, 256, 0, stream>>>(Wd, WdT);
    feat_kernel<<<B_*N_*NTILE*2, 256, 0, stream>>>(x, WdT, bd, tf, featc, pk_arr, w_arr, hist);
    scan_kernel<<<1, 1024, 0, stream>>>(hist, cursor);
    scatter_idx_kernel<<<(NPTS+255)/256, 256, 0, stream>>>(pk_arr, w_arr, cursor, spk, sw);
    gather_kernel<<<(NCHUNK+3)/4, 256, 0, stream>>>(spk, sw, cursor, featc, scat);
    transpose_k<<<B_*(NYY*NXX/64), 256, 0, stream>>>(scat, out);
}

// Round 6
// 426.269 us; speedup vs baseline: 1.2239x; 1.2239x over previous
//
#include <hip/hip_runtime.h>
#include <math.h>

#define B_   4
#define N_   6
#define CIN  512
#define CT   64
#define Dd   41
#define FH   16
#define FW   44
#define NPIX 704
#define NO   105
#define NOP  112          // padded output rows (bf16 weights)
#define NXX  128
#define NYY  128
#define NZZ  1
#define TOT  (B_*NZZ*NYY*NXX)   // 65536
#define NPTS (B_*N_*Dd*NPIX)    // 692736
#define NCHUNK ((NPTS+63)/64)   // 10824

#define PK_INVALID 0xFFFFFFFFu

#define XSTRIDE 72   // bf16 elems per s_xT row (16B-aligned, low-conflict)
#define WSTRIDE 72   // bf16 elems per s_wd row
#define FSTRIDE 66   // fp32 elems per s_feat row

typedef __attribute__((ext_vector_type(8))) short short8;
typedef __attribute__((ext_vector_type(4))) float f32x4;

// ---------------- helpers ----------------

__device__ __forceinline__ unsigned short f2bf(float f) {   // RNE
    unsigned u = __float_as_uint(f);
    u += 0x7FFFu + ((u >> 16) & 1u);
    return (unsigned short)(u >> 16);
}

__device__ __forceinline__ void inv3(const double* m, double* o) {
    double a=m[0],b=m[1],c=m[2],d=m[3],e=m[4],f=m[5],g=m[6],h=m[7],i=m[8];
    double A  =  (e*i - f*h);
    double Bc = -(d*i - f*g);
    double Cc =  (d*h - e*g);
    double det = a*A + b*Bc + c*Cc;
    double inv = 1.0/det;
    o[0]=A*inv;            o[1]=-(b*i - c*h)*inv;  o[2]= (b*f - c*e)*inv;
    o[3]=Bc*inv;           o[4]= (a*i - c*g)*inv;  o[5]=-(a*f - c*d)*inv;
    o[6]=Cc*inv;           o[7]=-(a*h - b*g)*inv;  o[8]= (a*e - b*d)*inv;
}

__device__ __forceinline__ int point_vox(const double* tfp, int b, int d, int hh, int ww) {
    const double DXD = (double)0.8f;
    const double LOX = (double)(-50.8f) - DXD*0.5;
    const double LOY = LOX;
    const double DZD = 20.0;
    const double LOZ = -10.0;
    double fx = (double)((float)(ww * (703.0/43.0)));
    double fy = (double)((float)(hh * 17.0));
    double fz = 4.0 + (double)d;
    double px = fx - tfp[21], py = fy - tfp[22], pz = fz - tfp[23];
    double qx = tfp[ 9]*px + tfp[10]*py + tfp[11]*pz;
    double qy = tfp[12]*px + tfp[13]*py + tfp[14]*pz;
    double qz = tfp[15]*px + tfp[16]*py + tfp[17]*pz;
    double rx = qx*qz, ry = qy*qz, rz = qz;
    double sx = tfp[0]*rx + tfp[1]*ry + tfp[2]*rz + tfp[18];
    double sy = tfp[3]*rx + tfp[4]*ry + tfp[5]*rz + tfp[19];
    double sz = tfp[6]*rx + tfp[7]*ry + tfp[8]*rz + tfp[20];
    int gx = (int)((sx - LOX) / DXD);
    int gy = (int)((sy - LOY) / DXD);
    int gz = (int)((sz - LOZ) / DZD);
    bool kept = (gx>=0) & (gx<NXX) & (gy>=0) & (gy<NYY) & (gz>=0) & (gz<NZZ);
    return kept ? (((b*NZZ + gz)*NYY + gy)*NXX + gx) : -1;
}

// ---------------- kernel A: per-(b,n) transforms (double) ----------------
__global__ void tf_kernel(const float* __restrict__ rots,
                          const float* __restrict__ trans,
                          const float* __restrict__ intrins,
                          const float* __restrict__ post_rots,
                          const float* __restrict__ post_trans,
                          double* __restrict__ tf) {
    int bn = threadIdx.x;
    if (bn >= B_*N_) return;
    double k[9], pr[9], r[9], ik[9], ipr[9], c[9];
    for (int i=0;i<9;i++) { k[i]=intrins[bn*9+i]; pr[i]=post_rots[bn*9+i]; r[i]=rots[bn*9+i]; }
    inv3(k, ik);
    inv3(pr, ipr);
    for (int i=0;i<3;i++)
        for (int j=0;j<3;j++) {
            double s = 0.0;
            for (int kk=0;kk<3;kk++) s += r[i*3+kk]*ik[kk*3+j];
            c[i*3+j] = s;
        }
    double* o = tf + bn*24;
    for (int i=0;i<9;i++) o[i]   = c[i];
    for (int i=0;i<9;i++) o[9+i] = ipr[i];
    for (int i=0;i<3;i++) o[18+i] = (double)trans[bn*3+i];
    for (int i=0;i<3;i++) o[21+i] = (double)post_trans[bn*3+i];
}

// ---------------- kernel A2: Wd[105][512] fp32 -> WdB[112][512] bf16 -------------
__global__ __launch_bounds__(256) void wdb_kernel(const float* __restrict__ Wd,
                                                  unsigned short* __restrict__ WdB) {
    int idx = blockIdx.x * 256 + threadIdx.x;
    if (idx >= NOP*CIN) return;
    int o = idx / CIN;
    WdB[idx] = (o < NO) ? f2bf(Wd[idx]) : (unsigned short)0;
}

// ---------------- kernel B: bf16 MFMA GEMM + softmax + geometry ------------------
// grid = 24 * 11 = 264 blocks; block = 256 thr = 4 waves; 64 pixels per block.
// wave wv owns pixels [pix0 + wv*16, +16); computes all 7 o-tiles (o = 0..111).
__global__ __launch_bounds__(256) void feat_kernel(
    const float* __restrict__ x, const unsigned short* __restrict__ WdB,
    const float* __restrict__ bd, const double* __restrict__ tf,
    float* __restrict__ featc, unsigned* __restrict__ pk_arr,
    float* __restrict__ w_arr, int* __restrict__ hist)
{
    __shared__ unsigned short s_xT[64*XSTRIDE];   // [pix][k] bf16    9.2 KB
    __shared__ unsigned short s_wd[NOP*WSTRIDE];  // [o][k]  bf16    16.1 KB
    __shared__ float  s_feat[NO*FSTRIDE];         // [o][pix] fp32   27.7 KB
    __shared__ float  s_red[4*64];
    __shared__ float  s_inv[64];
    __shared__ double s_tf[24];

    const int t    = threadIdx.x;
    const int l    = t & 63;
    const int wv   = t >> 6;
    const int col  = l & 15;
    const int quad = l >> 4;
    const int bn   = blockIdx.x / 11;
    const int tile = blockIdx.x % 11;
    const int pix0 = tile * 64;
    const int b    = bn / N_;

    if (t < 24) s_tf[t] = tf[bn*24 + t];

    f32x4 acc[7];
    #pragma unroll
    for (int i=0;i<7;i++) acc[i] = (f32x4){0.f,0.f,0.f,0.f};

    const float* xb = x + (size_t)bn * CIN * NPIX + pix0;
    const unsigned* wsrc = (const unsigned*)WdB;     // 2 bf16 per dword

    for (int k0 = 0; k0 < CIN; k0 += 64) {
        // ---- stage x tile (64 k x 64 pix fp32 -> bf16, transposed [pix][k]) ----
        {
            unsigned pkx[8];
            #pragma unroll
            for (int j = 0; j < 8; j++) {
                float a = xb[(size_t)(k0 + wv*16 + 2*j    )*NPIX + l];
                float c = xb[(size_t)(k0 + wv*16 + 2*j + 1)*NPIX + l];
                pkx[j] = (unsigned)f2bf(a) | ((unsigned)f2bf(c) << 16);
            }
            unsigned* dst = (unsigned*)&s_xT[l*XSTRIDE + wv*16];
            *(uint4*)(dst + 0) = make_uint4(pkx[0],pkx[1],pkx[2],pkx[3]);
            *(uint4*)(dst + 4) = make_uint4(pkx[4],pkx[5],pkx[6],pkx[7]);
        }
        // ---- stage Wd tile (112 o x 64 k bf16) ----
        {
            #pragma unroll
            for (int i = 0; i < 14; i++) {
                int o = wv*28 + 2*i + (l >> 5);
                unsigned v = wsrc[o*(CIN/2) + (k0 >> 1) + (l & 31)];
                *(unsigned*)&s_wd[o*WSTRIDE + (l & 31)*2] = v;
            }
        }
        __syncthreads();

        // ---- MFMA: 2 K-steps x 7 o-tiles ----
        #pragma unroll
        for (int ks = 0; ks < 2; ks++) {
            short8 bfr = *(const short8*)&s_xT[(wv*16 + col)*XSTRIDE + quad*8 + ks*32];
            #pragma unroll
            for (int t7 = 0; t7 < 7; t7++) {
                short8 afr = *(const short8*)&s_wd[(t7*16 + col)*WSTRIDE + quad*8 + ks*32];
                acc[t7] = __builtin_amdgcn_mfma_f32_16x16x32_bf16(afr, bfr, acc[t7], 0, 0, 0);
            }
        }
        __syncthreads();
    }

    // ---- epilogue: D -> s_feat (+bias). D: row=(lane>>4)*4+reg, col=lane&15 ----
    #pragma unroll
    for (int t7 = 0; t7 < 7; t7++) {
        #pragma unroll
        for (int r = 0; r < 4; r++) {
            int o = t7*16 + quad*4 + r;
            if (o < NO) s_feat[o*FSTRIDE + wv*16 + col] = acc[t7][r] + bd[o];
        }
    }
    __syncthreads();

    // ---- softmax over 41 depth rows (per pixel l, 4 waves cooperate) ----
    {
        float m = -3.0e38f;
        for (int d = wv; d < Dd; d += 4) m = fmaxf(m, s_feat[d*FSTRIDE + l]);
        s_red[wv*64 + l] = m;
        __syncthreads();
        float mm = fmaxf(fmaxf(s_red[l], s_red[64+l]), fmaxf(s_red[128+l], s_red[192+l]));
        float ssum = 0.0f;
        for (int d = wv; d < Dd; d += 4) {
            float e = expf(s_feat[d*FSTRIDE + l] - mm);
            s_feat[d*FSTRIDE + l] = e;
            ssum += e;
        }
        __syncthreads();             // all mm reads done before s_red overwrite
        s_red[wv*64 + l] = ssum;
        __syncthreads();
        s_inv[l] = 1.0f / (s_red[l] + s_red[64+l] + s_red[128+l] + s_red[192+l]);
        __syncthreads();
    }

    // ---- per-point weight + packed (vox,id) + histogram ----
    for (int id = t; id < Dd*64; id += 256) {
        int d  = id >> 6;
        int pp = id & 63;
        int pixg = pix0 + pp;
        int hh = pixg / FW, ww = pixg % FW;
        int pt = (bn*Dd + d)*NPIX + pixg;
        w_arr[pt] = s_feat[d*FSTRIDE + pp] * s_inv[pp];
        int vox = point_vox(s_tf, b, d, hh, ww);
        unsigned pix_id = (unsigned)(bn*NPIX + pixg);      // < 2^15
        pk_arr[pt] = (vox >= 0) ? (((unsigned)vox << 15) | pix_id) : PK_INVALID;
        if (vox >= 0) atomicAdd(&hist[vox], 1);
    }

    // ---- featc: [pix][64ch] float4-coalesced ----
    for (int idx = t; idx < 64*16; idx += 256) {
        int p  = idx >> 4;
        int c4 = (idx & 15) * 4;
        float4 v;
        v.x = s_feat[(Dd + c4 + 0)*FSTRIDE + p];
        v.y = s_feat[(Dd + c4 + 1)*FSTRIDE + p];
        v.z = s_feat[(Dd + c4 + 2)*FSTRIDE + p];
        v.w = s_feat[(Dd + c4 + 3)*FSTRIDE + p];
        *(float4*)&featc[((size_t)(bn*NPIX + pix0 + p))*CT + c4] = v;
    }
}

// ---------------- kernel C: exclusive scan over 65536 bins -> cursor ----------------
__global__ __launch_bounds__(1024) void scan_kernel(const int* __restrict__ hist,
                                                    int* __restrict__ cursor) {
    __shared__ int s[1024];
    const int t = threadIdx.x;
    const int CHUNK = TOT / 1024;   // 64
    int base_idx = t * CHUNK;
    int sum = 0;
    int local[64];
    #pragma unroll 8
    for (int j=0;j<CHUNK;j++) { local[j] = hist[base_idx+j]; sum += local[j]; }
    s[t] = sum;
    __syncthreads();
    for (int off=1; off<1024; off<<=1) {
        int v = (t >= off) ? s[t-off] : 0;
        __syncthreads();
        s[t] += v;
        __syncthreads();
    }
    int run = (t==0) ? 0 : s[t-1];
    #pragma unroll 8
    for (int j=0;j<CHUNK;j++) {
        cursor[base_idx+j] = run;
        run += local[j];
    }
}

// ---------------- kernel D: scatter packed records into sorted order ----------------
__global__ __launch_bounds__(256) void scatter_idx_kernel(
    const unsigned* __restrict__ pk_arr, const float* __restrict__ w_arr,
    int* __restrict__ cursor, unsigned* __restrict__ spk,
    float* __restrict__ sw)
{
    int pt = blockIdx.x * 256 + threadIdx.x;
    if (pt >= NPTS) return;
    unsigned pk = pk_arr[pt];
    if (pk != PK_INVALID) {
        int v = pk >> 15;
        int pos = atomicAdd(&cursor[v], 1);
        spk[pos] = pk;
        sw[pos]  = w_arr[pt];
    }
}

// ---------------- kernel E: balanced segmented gather -> scat[vox][ct] ----------------
__global__ __launch_bounds__(256) void gather_kernel(
    const unsigned* __restrict__ spk, const float* __restrict__ sw,
    const int* __restrict__ cursor, const float* __restrict__ featc,
    float* __restrict__ scat)
{
    const int t  = threadIdx.x;
    const int wv = t >> 6;
    const int l  = t & 63;
    const int chunk = blockIdx.x * 4 + wv;
    const int base  = chunk * 64;
    const int Np = cursor[TOT-1];          // total valid points
    if (base >= Np) return;
    int cnt = Np - base; if (cnt > 64) cnt = 64;

    unsigned pk = 0; float w = 0.0f;
    if (l < cnt) { pk = spk[base + l]; w = sw[base + l]; }
    unsigned pkm = __shfl(pk, (l == 0) ? 0 : (l - 1));
    unsigned long long starts =
        __ballot((l > 0) && (l < cnt) && ((pk >> 15) != (pkm >> 15)));

    unsigned long long m = starts;
    int rs = 0;
    while (rs < cnt) {
        int re = m ? (__ffsll((unsigned long long)m) - 1) : cnt;
        if (m) m &= m - 1;
        float acc = 0.0f;
        for (int j = rs; j < re; j++) {
            unsigned pkj = __shfl(pk, j);
            float    wj  = __shfl(w, j);
            unsigned id  = pkj & 0x7FFFu;
            acc += wj * featc[(size_t)id * CT + l];
        }
        unsigned vrun = __shfl(pk, rs) >> 15;
        float* dst = scat + (size_t)vrun * CT + l;
        if (rs == 0 || re == cnt) {
            unsafeAtomicAdd(dst, acc);      // run may continue in adjacent chunk
        } else {
            *dst = acc;                     // voxel wholly owned by this chunk
        }
        rs = re;
    }
}

// ---------------- kernel F: transpose (b,pix,ct) -> (b,ct,pix) ----------------
__global__ __launch_bounds__(256) void transpose_k(const float* __restrict__ scat,
                                                   float* __restrict__ out) {
    __shared__ float tile[64][65];
    int b  = blockIdx.x >> 8;
    int t0 = (blockIdx.x & 255) * 64;
    const float* src = scat + (size_t)b * (NYY*NXX) * CT;
    #pragma unroll
    for (int i=0;i<16;i++) {
        int idx = threadIdx.x + i*256;
        int p = idx >> 6, c = idx & 63;
        tile[p][c] = src[(size_t)(t0+p)*CT + c];
    }
    __syncthreads();
    float* dst = out + (size_t)b * CT * (NYY*NXX);
    #pragma unroll
    for (int i=0;i<16;i++) {
        int idx = threadIdx.x + i*256;
        int c = idx >> 6, p = idx & 63;
        dst[(size_t)c*(NYY*NXX) + t0 + p] = tile[p][c];
    }
}

// ---------------- launcher ----------------
extern "C" void kernel_launch(void* const* d_in, const int* in_sizes, int n_in,
                              void* d_out, int out_size, void* d_ws, size_t ws_size,
                              hipStream_t stream) {
    const float* x          = (const float*)d_in[0];
    const float* rots       = (const float*)d_in[1];
    const float* trans      = (const float*)d_in[2];
    const float* intrins    = (const float*)d_in[3];
    const float* post_rots  = (const float*)d_in[4];
    const float* post_trans = (const float*)d_in[5];
    const float* Wd         = (const float*)d_in[6];
    const float* bd         = (const float*)d_in[7];
    float* out = (float*)d_out;

    char* ws = (char*)d_ws;
    float*          featc  = (float*)ws;          ws += (size_t)B_*N_*NPIX*CT*4;   // 4.33 MB
    unsigned*       pk_arr = (unsigned*)ws;       ws += (size_t)NPTS*4;            // 2.77 MB
    float*          w_arr  = (float*)ws;          ws += (size_t)NPTS*4;            // 2.77 MB
    unsigned*       spk    = (unsigned*)ws;       ws += (size_t)NPTS*4;            // 2.77 MB
    float*          sw     = (float*)ws;          ws += (size_t)NPTS*4;            // 2.77 MB
    float*          scat   = (float*)ws;          ws += (size_t)TOT*CT*4;          // 16.78 MB
    int*            hist   = (int*)ws;            ws += (size_t)TOT*4;             // 0.26 MB
    int*            cursor = (int*)ws;            ws += (size_t)TOT*4;             // 0.26 MB
    double*         tf     = (double*)ws;         ws += (size_t)B_*N_*24*8;        // 4.6 KB
    unsigned short* WdB    = (unsigned short*)ws; ws += (size_t)NOP*CIN*2;         // 0.11 MB

    hipMemsetAsync(scat, 0, (size_t)TOT*CT*4, stream);
    hipMemsetAsync(hist, 0, (size_t)TOT*4, stream);
    tf_kernel<<<1, 64, 0, stream>>>(rots, trans, intrins, post_rots, post_trans, tf);
    wdb_kernel<<<(NOP*CIN+255)/256, 256, 0, stream>>>(Wd, WdB);
    feat_kernel<<<B_*N_*11, 256, 0, stream>>>(x, WdB, bd, tf, featc, pk_arr, w_arr, hist);
    scan_kernel<<<1, 1024, 0, stream>>>(hist, cursor);
    scatter_idx_kernel<<<(NPTS+255)/256, 256, 0, stream>>>(pk_arr, w_arr, cursor, spk, sw);
    gather_kernel<<<(NCHUNK+3)/4, 256, 0, stream>>>(spk, sw, cursor, featc, scat);
    transpose_k<<<B_*(NYY*NXX/64), 256, 0, stream>>>(scat, out);
}